// Round 3
// baseline (114.993 us; speedup 1.0000x reference)
//
#include <hip/hip_runtime.h>
#include <hip/hip_bf16.h>

// DifferenceOfGaussians on MI355X — round 10: vdog rewritten as 8-wave
// LDS-staged blocks. Keep the proven 4-kernel structure (round 5/6:
// device-scope grid barriers cost ~100us each on gfx950 — do not re-fuse).
//
// Round 9 post-mortem (the key discovery): vdog charted at 42.84us
// (VALUBusy 16.7%, HBM 6.3%, Occupancy 8.85%, VGPR 132 => acc[32]+win[32]
// fp64 ring spilled). Total barely moved vs round 8 => vdog was ~41-42us in
// ALL prior rounds, hidden just under the 42.9us poison-fill top-5 cutoff.
// It is LATENCY-bound: 1-wave blocks, ~2.8 resident waves/CU, serial
// stride-2KB column loads from L3 (h written by other XCDs, per-XCD L2s
// non-coherent). fp64-FMA floor ~7us; the other ~35us was un-hidden latency.
//
// Fix: 512-thread (8-wave) vdog blocks staging the two h row-bands into LDS
// with coalesced ~14-deep independent loads, then computing from LDS via a
// 4-slot register ring (per tap: 1 LDS val + 1 broadcast weight + 4 fp64
// FMA => VALU-bound). LDS 60.9KB/block -> 2 blocks/CU = 16 waves/CU.
// BITWISE identical dog: same staged values, same ascending tap order per
// output, conv0-then-conv1 order, boundary taps exact fma(0,finite,acc)
// no-ops, read ranges identical (max h row 599 < 640, same as before).
// fp64 accumulation throughout (absmax 0.0 across all passing rounds —
// peak-set ordering is the real correctness risk; do not weaken numerics).
//
// Workspace (bytes):
//   OFF_H    : float h[14][640][512]   (rows 43..554 data, 0..42 & 555..597
//              zeroed guards, 598..639 read-but-zero-weight)
//   OFF_DOG  : float dog[13][512][512]
//   OFF_BITS : u64  rowbits[6656][8]
//   OFF_GCNT : int  gcnt[832]

#define OFF_H    0
#define OFF_DOG  18350080
#define OFF_BITS 31981568
#define OFF_GCNT 32407552

#define HROWS 640
#define HPAD  43
#define NSIG 13
#define MAXPEAKS 32768

// Build normalized (optionally sign-flipped) weights, zero-padded to 96,
// using one 64-lane wave. Matches reference exp(-(d/(2s))^2) / sum.
__device__ __forceinline__ void make_w(float s, double sgn, double* wl, int lane) {
    int r = (int)(4.0f * s + 0.5f);
    int n = 2 * r + 1;
    double v0 = 0.0, v1 = 0.0;
    double sd = (double)s;
    if (lane < n) {
        double d = (double)(lane - r), q = d / (2.0 * sd);
        v0 = exp(-q * q);
    }
    if (lane + 64 < n) {
        double d = (double)(lane + 64 - r), q = d / (2.0 * sd);
        v1 = exp(-q * q);
    }
    double part = v0 + v1;
    for (int m = 1; m < 64; m <<= 1) part += __shfl_xor(part, m);
    double inv = sgn / part;
    wl[lane] = v0 * inv;
    if (lane + 64 < 96) wl[lane + 64] = v1 * inv;
}

// ---- 1: horizontal blur + guard zeroing; 16 outputs/thread ----
// block 256 = 8 rows x 32 threads; grid (64 rowgroups, 14 planes), heavy first
__global__ __launch_bounds__(256) void hpass(const float* __restrict__ x,
                                             const float* __restrict__ sigma_list,
                                             float* __restrict__ h) {
    const int i = 13 - blockIdx.y;        // heavy plane first
    const int t = threadIdx.x;
    float s = sigma_list[i];
    int r = (int)(4.0f * s + 0.5f);
    int n = 2 * r + 1;
    int nc8 = (n + 7) & ~7;               // 8-granular tap count

    __shared__ double wl[96];
    if (t < 64) make_w(s, +1.0, wl, t);

    // zero this block's share of the 86 guard rows (64 blocks x 688 = 86*512)
    {
        float* hp = h + i * (HROWS * 512);
        for (int k = t; k < 688; k += 256) {
            int f = blockIdx.x * 688 + k;      // 0..44031
            int g = f >> 9, xc = f & 511;      // g in 0..85
            int row = (g < HPAD) ? g : (g + 512);   // 0..42, 555..597
            hp[row * 512 + xc] = 0.0f;
        }
    }

    // stage 8 zero-padded rows, skewed (addr = p + p/16)
    __shared__ float rowp[8][648];
    int y8 = blockIdx.x * 8;
    for (int rr = 0; rr < 8; ++rr)
        for (int k = t; k < 608; k += 256) {
            int gx = k - 43;
            float val = ((unsigned)gx < 512u) ? x[(y8 + rr) * 512 + gx] : 0.0f;
            rowp[rr][k + (k >> 4)] = val;
        }
    __syncthreads();

    int tsub = t & 31, row = t >> 5;
    int xb = tsub * 16;
    int P0 = 43 - r + xb;
    double acc[16], win[16];
#pragma unroll
    for (int j = 0; j < 16; ++j) acc[j] = 0.0;
#pragma unroll
    for (int sl = 0; sl < 16; ++sl) {
        int p = P0 + sl;
        win[sl] = (double)rowp[row][p + (p >> 4)];
    }
    int full = nc8 & ~15;                 // multiple of 16
    for (int dc = 0; dc < full; dc += 16) {
#pragma unroll
        for (int k = 0; k < 16; ++k) {
            double wd = wl[dc + k];
#pragma unroll
            for (int j = 0; j < 16; ++j)
                acc[j] = fma(wd, win[(k + j) & 15], acc[j]);
            int p = P0 + dc + k + 16;
            win[k] = (double)rowp[row][p + (p >> 4)];
        }
    }
    if (nc8 & 8) {                        // one 8-wide tail
#pragma unroll
        for (int k = 0; k < 8; ++k) {
            double wd = wl[full + k];
#pragma unroll
            for (int j = 0; j < 16; ++j)
                acc[j] = fma(wd, win[(k + j) & 15], acc[j]);
            int p = P0 + full + k + 16;   // p <= 599 < 608 staged
            win[k] = (double)rowp[row][p + (p >> 4)];
        }
    }
    float* hp = h + (i * HROWS + HPAD + y8 + row) * 512 + xb;
#pragma unroll
    for (int j = 0; j < 16; ++j) hp[j] = (float)acc[j];
}

// ---- 2: vertical blur pair + DoG; 8-wave LDS-staged blocks ----
// grid (8 x-tiles, 16 y-tiles of 32 rows, 13 planes) = 1664 blocks x 512.
// Stage h[di] rows [y0-r0, y0-r0+nc0+31] and h[di+1] rows [y0-r1, ...+nc1+31]
// into LDS (coalesced, ~14 independent loads/thread), then wave w computes
// output rows 4w..4w+3 via a 4-slot register ring over LDS rows.
__global__ __launch_bounds__(512) void vdog(const float* __restrict__ h,
                                            const float* __restrict__ sigma_list,
                                            float* __restrict__ dog) {
    const int di = 12 - blockIdx.z;       // heavy plane first
    const int t = threadIdx.x;
    const int w = t >> 6, lane = t & 63;
    const int x0 = blockIdx.x * 64;
    const int y0 = blockIdx.y * 32;
    float s0 = sigma_list[di], s1 = sigma_list[di + 1];
    int r0 = (int)(4.0f * s0 + 0.5f), n0 = 2 * r0 + 1, nc0 = (n0 + 7) & ~7;  // <= 80
    int r1 = (int)(4.0f * s1 + 0.5f), n1 = 2 * r1 + 1, nc1 = (n1 + 7) & ~7;  // <= 88

    __shared__ float ht0[112][64];        // nc0+32 <= 112 rows used
    __shared__ float ht1[120][64];        // nc1+32 <= 120 rows used
    __shared__ double wl0[96], wl1[96];

    if (w == 0) make_w(s0, +1.0, wl0, lane);
    else if (w == 1) make_w(s1, -1.0, wl1, lane);   // negated: acc = conv0 - conv1

    // stage both row-bands; max global h row = 554 + (nc-r) <= 599 < 640,
    // identical read range to the previous per-lane column walk.
    {
        const float* p0 = h + di * (HROWS * 512) + (HPAD + y0 - r0) * 512 + x0 + lane;
        int rows0 = nc0 + 32;
        for (int rr = w; rr < rows0; rr += 8)
            ht0[rr][lane] = p0[rr * 512];
        const float* p1 = h + (di + 1) * (HROWS * 512) + (HPAD + y0 - r1) * 512 + x0 + lane;
        int rows1 = nc1 + 32;
        for (int rr = w; rr < rows1; rr += 8)
            ht1[rr][lane] = p1[rr * 512];
    }
    __syncthreads();

    double acc[4];
#pragma unroll
    for (int jj = 0; jj < 4; ++jj) acc[jj] = 0.0;

    // conv0: taps ascending, ring slot (k+jj)&3 holds LDS row 4w+k+jj
    {
        double win[4];
#pragma unroll
        for (int jj = 0; jj < 4; ++jj) win[jj] = (double)ht0[4 * w + jj][lane];
        for (int kk = 0; kk < nc0; kk += 4) {
#pragma unroll
            for (int p = 0; p < 4; ++p) {
                double wd = wl0[kk + p];
#pragma unroll
                for (int jj = 0; jj < 4; ++jj)
                    acc[jj] = fma(wd, win[(p + jj) & 3], acc[jj]);
                win[p] = (double)ht0[4 * w + kk + p + 4][lane];  // row <= nc0+31
            }
        }
    }
    // conv1 (weights pre-negated)
    {
        double win[4];
#pragma unroll
        for (int jj = 0; jj < 4; ++jj) win[jj] = (double)ht1[4 * w + jj][lane];
        for (int kk = 0; kk < nc1; kk += 4) {
#pragma unroll
            for (int p = 0; p < 4; ++p) {
                double wd = wl1[kk + p];
#pragma unroll
                for (int jj = 0; jj < 4; ++jj)
                    acc[jj] = fma(wd, win[(p + jj) & 3], acc[jj]);
                win[p] = (double)ht1[4 * w + kk + p + 4][lane];  // row <= nc1+31
            }
        }
    }

    double sg = (double)s0;
    float* dp = dog + (di * 512 + y0 + 4 * w) * 512 + x0 + lane;
#pragma unroll
    for (int jj = 0; jj < 4; ++jj) dp[jj * 512] = (float)(acc[jj] * sg);
}

// ---- 3: 3x3x3 peak detect, SCALE-PAIRED; 8-row tile; group counts ----
// grid (64 y-tiles, 6), block 512. Block z handles scales sA=2z+1 and
// sA+1 (z<5); shares the 4 dog planes sA-1..sA+2 across both outputs.
// z==0 also zeroes scale-0 rowbits, z==5 zeroes scale-12.
__global__ __launch_bounds__(512) void detect(const float* __restrict__ dog,
                                              unsigned long long* __restrict__ rowbits,
                                              int* __restrict__ gcnt) {
    const int z = blockIdx.y;             // 0..5
    const int sA = 2 * z + 1;             // 1,3,5,7,9,11
    const bool hasB = (sA < 11);
    const int bx = blockIdx.x;
    const int y0 = bx * 8;
    const int t = threadIdx.x;
    const int w = t >> 6, lane = t & 63;

    if (z == 0) {                         // border scale 0: zeros
        if (t < 64) rowbits[(0 * 512 + y0 + (t >> 3)) * 8 + (t & 7)] = 0ull;
        if (t == 0) gcnt[0 * 64 + bx] = 0;
    } else if (z == 5) {                  // border scale 12: zeros
        if (t < 64) rowbits[(12 * 512 + y0 + (t >> 3)) * 8 + (t & 7)] = 0ull;
        if (t == 0) gcnt[12 * 64 + bx] = 0;
    }

    const int p0 = sA - 1;
    float rm[4][8];                       // per-plane 3-row column max
    float vA[8], vB[8];                   // center values for scales sA, sA+1
#pragma unroll
    for (int pp = 0; pp < 4; ++pp) {
        if (pp == 3 && !hasB) {
#pragma unroll
            for (int k = 0; k < 8; ++k) rm[3][k] = -3.0e38f;
        } else {
            const float* dp = dog + (p0 + pp) * (512 * 512) + t;
            float val[10];
#pragma unroll
            for (int q = 0; q < 10; ++q) {
                int yy = y0 - 1 + q;
                val[q] = ((unsigned)yy < 512u) ? dp[yy * 512] : -3.0e38f;
            }
#pragma unroll
            for (int k = 0; k < 8; ++k)
                rm[pp][k] = fmaxf(val[k], fmaxf(val[k + 1], val[k + 2]));
            if (pp == 1) {
#pragma unroll
                for (int k = 0; k < 8; ++k) vA[k] = val[k + 1];
            }
            if (pp == 2) {
#pragma unroll
                for (int k = 0; k < 8; ++k) vB[k] = val[k + 1];
            }
        }
    }

    __shared__ float cml[2][8][512];      // 32 KB
    __shared__ int cnt[2][8][8];
#pragma unroll
    for (int k = 0; k < 8; ++k) {
        cml[0][k][t] = fmaxf(rm[0][k], fmaxf(rm[1][k], rm[2][k]));
        cml[1][k][t] = fmaxf(rm[1][k], fmaxf(rm[2][k], rm[3][k]));  // rm[3]=-3e38 when !hasB
    }
    __syncthreads();

#pragma unroll
    for (int k = 0; k < 8; ++k) {         // scale sA
        int y = y0 + k;
        bool peak = false;
        if (t >= 1 && t <= 510 && y >= 1 && y <= 510) {
            float v = vA[k];
            if (v > 0.001f) {
                float mx = fmaxf(cml[0][k][t - 1], fmaxf(cml[0][k][t], cml[0][k][t + 1]));
                peak = (v >= mx);         // mx includes v
            }
        }
        unsigned long long m = __ballot(peak);
        if (lane == 0) {
            rowbits[(sA * 512 + y) * 8 + w] = m;
            cnt[0][k][w] = __popcll(m);
        }
    }
    if (hasB) {
        const int sB = sA + 1;
#pragma unroll
        for (int k = 0; k < 8; ++k) {     // scale sA+1
            int y = y0 + k;
            bool peak = false;
            if (t >= 1 && t <= 510 && y >= 1 && y <= 510) {
                float v = vB[k];
                if (v > 0.001f) {
                    float mx = fmaxf(cml[1][k][t - 1], fmaxf(cml[1][k][t], cml[1][k][t + 1]));
                    peak = (v >= mx);
                }
            }
            unsigned long long m = __ballot(peak);
            if (lane == 0) {
                rowbits[(sB * 512 + y) * 8 + w] = m;
                cnt[1][k][w] = __popcll(m);
            }
        }
    }
    __syncthreads();
    if (t == 0) {
        int c = 0;
#pragma unroll
        for (int k = 0; k < 8; ++k)
#pragma unroll
            for (int q = 0; q < 8; ++q) c += cnt[0][k][q];
        gcnt[sA * 64 + bx] = c;
        if (hasB) {
            c = 0;
#pragma unroll
            for (int k = 0; k < 8; ++k)
#pragma unroll
                for (int q = 0; q < 8; ++q) c += cnt[1][k][q];
            gcnt[(sA + 1) * 64 + bx] = c;
        }
    }
}

// ---- 4: ordered emit + padding fill; wave-shuffle group reduce ----
// grid 832 blocks x 512 (block b covers scale b/64, rows (b%64)*8 .. +7)
__global__ __launch_bounds__(512) void emit(const unsigned long long* __restrict__ rowbits,
                                            const int* __restrict__ gcnt,
                                            const float* __restrict__ sigma_list,
                                            float* __restrict__ out) {
    const int b = blockIdx.x;
    const int s = b >> 6;
    const int y0 = (b & 63) * 8;
    const int t = threadIdx.x;
    const int w = t >> 6, lane = t & 63;

    // zero-peak blocks outside the padding range have nothing to do
    if (b >= 64 && gcnt[b] == 0) return;

    __shared__ unsigned long long m[64];   // [row k][word q]
    __shared__ int pre[64];                // exclusive word prefix (row-major)
    __shared__ int wsumA[8], wsumB[8];

    if (t < 64) m[t] = rowbits[(s * 512 + y0 + (t >> 3)) * 8 + (t & 7)];

    int pa = 0, pb = 0;
    {
        int c0 = (t < 832) ? gcnt[t] : 0;
        int i1 = t + 512;
        int c1 = (i1 < 832) ? gcnt[i1] : 0;
        pb = c0 + c1;
        if (t < b) pa += c0;
        if (i1 < b) pa += c1;
    }
#pragma unroll
    for (int off = 32; off > 0; off >>= 1) {   // 64-lane wave reduce
        pa += __shfl_down(pa, off);
        pb += __shfl_down(pb, off);
    }
    if (lane == 0) { wsumA[w] = pa; wsumB[w] = pb; }

    if (t < 64) {                          // wave-0 exclusive scan of word counts
        int wc = (int)__popcll(m[t]);
        int inc = wc;
        for (int off = 1; off < 64; off <<= 1) {
            int v = __shfl_up(inc, off);
            if (lane >= off) inc += v;
        }
        pre[t] = inc - wc;
    }
    __syncthreads();

    int gbase = 0, tot = 0;
#pragma unroll
    for (int i = 0; i < 8; ++i) { gbase += wsumA[i]; tot += wsumB[i]; }
    tot = min(tot, MAXPEAKS);

#pragma unroll
    for (int k = 0; k < 8; ++k) {
        int widx = k * 8 + (t >> 6);
        unsigned long long mw = m[widx];
        if ((mw >> lane) & 1ull) {
            int pos = gbase + pre[widx] + (int)__popcll(mw & ((1ull << lane) - 1ull));
            if (pos < MAXPEAKS) {
                out[pos * 3 + 0] = sigma_list[s];
                out[pos * 3 + 1] = (float)(y0 + k);
                out[pos * 3 + 2] = (float)t;
            }
        }
    }

    int idx = b * 512 + t;                 // blocks 0..63 cover all 32768 rows
    if (idx < MAXPEAKS && idx >= tot) {
        out[idx * 3 + 0] = sigma_list[0];
        out[idx * 3 + 1] = 0.0f;
        out[idx * 3 + 2] = 0.0f;
    }
}

extern "C" void kernel_launch(void* const* d_in, const int* in_sizes, int n_in,
                              void* d_out, int out_size, void* d_ws, size_t ws_size,
                              hipStream_t stream) {
    const float* x     = (const float*)d_in[0];   // [1,1,512,512]
    const float* sigma = (const float*)d_in[2];   // [14]
    float* out = (float*)d_out;                   // [32768,3]

    char* ws = (char*)d_ws;
    float* h                     = (float*)(ws + OFF_H);
    float* dog                   = (float*)(ws + OFF_DOG);
    unsigned long long* rowbits  = (unsigned long long*)(ws + OFF_BITS);
    int* gcnt                    = (int*)(ws + OFF_GCNT);

    hpass<<<dim3(64, 14), 256, 0, stream>>>(x, sigma, h);
    vdog<<<dim3(8, 16, 13), 512, 0, stream>>>(h, sigma, dog);
    detect<<<dim3(64, 6), 512, 0, stream>>>(dog, rowbits, gcnt);
    emit<<<832, 512, 0, stream>>>(rowbits, gcnt, sigma, out);
}

// Round 4
// 110.417 us; speedup vs baseline: 1.0414x; 1.0414x over previous
//
#include <hip/hip_runtime.h>
#include <hip/hip_bf16.h>

// DifferenceOfGaussians on MI355X — round 11: REVERT to the round-8
// configuration (best measured: 110.48us; prior session best 110.3us).
//
// Session decomposition (rounds 8-10 evidence):
//   - dur_us ~= 2x 256MiB harness poison fills (~88us @ 76-78% HBM peak,
//     memory-roofline-bound) + ~22us kernels+launch gaps.
//   - Serial-sum contradiction (r9: fills 86.6 + vdog 42.8 > total 111.6)
//     proves rocprof per-kernel durations are inflated by replay
//     serialization/cold-cache; do NOT trust them as timed-run costs.
//   - Three structurally different vdog variants (16-row ring / 32-row ring
//     / 8-wave LDS-staged) all landed within fill noise (+-1.5us) of 110.5;
//     r10's LDS version was ~2-3us WORSE in the warm timed regime. Reverted.
//   - Round 5/6: single fused kernel with device-scope grid barriers costs
//     ~100us PER BARRIER on gfx950 (L2-thrash across non-coherent XCDs).
//     Do not re-fuse. detect->emit cross-block dep forbids merging without
//     a grid barrier.
//
// Structure: guard-padded h => unconditional vdog loads; 4 kernels:
// hpass, vdog, detect (scale-paired), emit (wave-shuffle reduce).
// fp64 accumulation throughout (absmax 0.0 across all passing rounds —
// peak-set ordering is the real correctness risk; do not weaken numerics).
//
// Workspace (bytes):
//   OFF_H    : float h[14][640][512]   (rows 43..554 data, 0..42 & 555..597
//              zeroed guards, 598..639 read-but-zero-weight)
//   OFF_DOG  : float dog[13][512][512]
//   OFF_BITS : u64  rowbits[6656][8]
//   OFF_GCNT : int  gcnt[832]

#define OFF_H    0
#define OFF_DOG  18350080
#define OFF_BITS 31981568
#define OFF_GCNT 32407552

#define HROWS 640
#define HPAD  43
#define NSIG 13
#define MAXPEAKS 32768

// Build normalized (optionally sign-flipped) weights, zero-padded to 96,
// using one 64-lane wave. Matches reference exp(-(d/(2s))^2) / sum.
__device__ __forceinline__ void make_w(float s, double sgn, double* wl, int lane) {
    int r = (int)(4.0f * s + 0.5f);
    int n = 2 * r + 1;
    double v0 = 0.0, v1 = 0.0;
    double sd = (double)s;
    if (lane < n) {
        double d = (double)(lane - r), q = d / (2.0 * sd);
        v0 = exp(-q * q);
    }
    if (lane + 64 < n) {
        double d = (double)(lane + 64 - r), q = d / (2.0 * sd);
        v1 = exp(-q * q);
    }
    double part = v0 + v1;
    for (int m = 1; m < 64; m <<= 1) part += __shfl_xor(part, m);
    double inv = sgn / part;
    wl[lane] = v0 * inv;
    if (lane + 64 < 96) wl[lane + 64] = v1 * inv;
}

// ---- 1: horizontal blur + guard zeroing; 16 outputs/thread ----
// block 256 = 8 rows x 32 threads; grid (64 rowgroups, 14 planes), heavy first
__global__ __launch_bounds__(256) void hpass(const float* __restrict__ x,
                                             const float* __restrict__ sigma_list,
                                             float* __restrict__ h) {
    const int i = 13 - blockIdx.y;        // heavy plane first
    const int t = threadIdx.x;
    float s = sigma_list[i];
    int r = (int)(4.0f * s + 0.5f);
    int n = 2 * r + 1;
    int nc8 = (n + 7) & ~7;               // 8-granular tap count

    __shared__ double wl[96];
    if (t < 64) make_w(s, +1.0, wl, t);

    // zero this block's share of the 86 guard rows (64 blocks x 688 = 86*512)
    {
        float* hp = h + i * (HROWS * 512);
        for (int k = t; k < 688; k += 256) {
            int f = blockIdx.x * 688 + k;      // 0..44031
            int g = f >> 9, xc = f & 511;      // g in 0..85
            int row = (g < HPAD) ? g : (g + 512);   // 0..42, 555..597
            hp[row * 512 + xc] = 0.0f;
        }
    }

    // stage 8 zero-padded rows, skewed (addr = p + p/16)
    __shared__ float rowp[8][648];
    int y8 = blockIdx.x * 8;
    for (int rr = 0; rr < 8; ++rr)
        for (int k = t; k < 608; k += 256) {
            int gx = k - 43;
            float val = ((unsigned)gx < 512u) ? x[(y8 + rr) * 512 + gx] : 0.0f;
            rowp[rr][k + (k >> 4)] = val;
        }
    __syncthreads();

    int tsub = t & 31, row = t >> 5;
    int xb = tsub * 16;
    int P0 = 43 - r + xb;
    double acc[16], win[16];
#pragma unroll
    for (int j = 0; j < 16; ++j) acc[j] = 0.0;
#pragma unroll
    for (int sl = 0; sl < 16; ++sl) {
        int p = P0 + sl;
        win[sl] = (double)rowp[row][p + (p >> 4)];
    }
    int full = nc8 & ~15;                 // multiple of 16
    for (int dc = 0; dc < full; dc += 16) {
#pragma unroll
        for (int k = 0; k < 16; ++k) {
            double wd = wl[dc + k];
#pragma unroll
            for (int j = 0; j < 16; ++j)
                acc[j] = fma(wd, win[(k + j) & 15], acc[j]);
            int p = P0 + dc + k + 16;
            win[k] = (double)rowp[row][p + (p >> 4)];
        }
    }
    if (nc8 & 8) {                        // one 8-wide tail
#pragma unroll
        for (int k = 0; k < 8; ++k) {
            double wd = wl[full + k];
#pragma unroll
            for (int j = 0; j < 16; ++j)
                acc[j] = fma(wd, win[(k + j) & 15], acc[j]);
            int p = P0 + full + k + 16;   // p <= 599 < 608 staged
            win[k] = (double)rowp[row][p + (p >> 4)];
        }
    }
    float* hp = h + (i * HROWS + HPAD + y8 + row) * 512 + xb;
#pragma unroll
    for (int j = 0; j < 16; ++j) hp[j] = (float)acc[j];
}

// Unconditional guarded conv: bp points at padded row (y0 - r + HPAD).
// nc8 is the 8-granular tap count; full-16 chunks + optional 8-tail keeps
// every win[] index compile-time (no scratch spill).
__device__ __forceinline__ void conv_acc(const float* __restrict__ bp,
                                         int nc8, const double* __restrict__ wl,
                                         double (&acc)[16]) {
    double win[16];
#pragma unroll
    for (int sl = 0; sl < 16; ++sl) win[sl] = (double)bp[sl * 512];
    int full = nc8 & ~15;
    for (int dc = 0; dc < full; dc += 16) {
        const float* rp = bp + (dc + 16) * 512;
#pragma unroll
        for (int k = 0; k < 16; ++k) {
            double wd = wl[dc + k];
#pragma unroll
            for (int j = 0; j < 16; ++j)
                acc[j] = fma(wd, win[(k + j) & 15], acc[j]);
            win[k] = (double)rp[k * 512];
        }
    }
    if (nc8 & 8) {
        const float* rp = bp + (full + 16) * 512;   // rows <= 599 < 640 (guards)
#pragma unroll
        for (int k = 0; k < 8; ++k) {
            double wd = wl[full + k];
#pragma unroll
            for (int j = 0; j < 16; ++j)
                acc[j] = fma(wd, win[(k + j) & 15], acc[j]);
            win[k] = (double)rp[k * 512];
        }
    }
}

// ---- 2: vertical blur pair + DoG; 1-wave blocks, heavy plane first ----
// grid (8 x-tiles, 32 y-tiles, 13 planes) = 3328 blocks of 64 threads
__global__ __launch_bounds__(64) void vdog(const float* __restrict__ h,
                                           const float* __restrict__ sigma_list,
                                           float* __restrict__ dog) {
    const int di = 12 - blockIdx.z;
    const int lane = threadIdx.x;
    const int x = blockIdx.x * 64 + lane;
    const int y0 = blockIdx.y * 16;
    float s0 = sigma_list[di], s1 = sigma_list[di + 1];
    int r0 = (int)(4.0f * s0 + 0.5f), n0 = 2 * r0 + 1, nc0 = (n0 + 7) & ~7;
    int r1 = (int)(4.0f * s1 + 0.5f), n1 = 2 * r1 + 1, nc1 = (n1 + 7) & ~7;
    __shared__ double wl0[96], wl1[96];
    make_w(s0, +1.0, wl0, lane);
    make_w(s1, -1.0, wl1, lane);          // negated: acc = conv0 - conv1
    __syncthreads();
    double acc[16];
#pragma unroll
    for (int j = 0; j < 16; ++j) acc[j] = 0.0;
    const float* hp0 = h + di * (HROWS * 512);
    conv_acc(hp0 + (HPAD + y0 - r0) * 512 + x, nc0, wl0, acc);
    const float* hp1 = hp0 + HROWS * 512;
    conv_acc(hp1 + (HPAD + y0 - r1) * 512 + x, nc1, wl1, acc);
    double sg = (double)s0;
    float* dp = dog + (di * 512 + y0) * 512 + x;
#pragma unroll
    for (int j = 0; j < 16; ++j) dp[j * 512] = (float)(acc[j] * sg);
}

// ---- 3: 3x3x3 peak detect, SCALE-PAIRED; 8-row tile; group counts ----
// grid (64 y-tiles, 6), block 512. Block z handles scales sA=2z+1 and
// sA+1 (z<5); shares the 4 dog planes sA-1..sA+2 across both outputs.
// z==0 also zeroes scale-0 rowbits, z==5 zeroes scale-12.
__global__ __launch_bounds__(512) void detect(const float* __restrict__ dog,
                                              unsigned long long* __restrict__ rowbits,
                                              int* __restrict__ gcnt) {
    const int z = blockIdx.y;             // 0..5
    const int sA = 2 * z + 1;             // 1,3,5,7,9,11
    const bool hasB = (sA < 11);
    const int bx = blockIdx.x;
    const int y0 = bx * 8;
    const int t = threadIdx.x;
    const int w = t >> 6, lane = t & 63;

    if (z == 0) {                         // border scale 0: zeros
        if (t < 64) rowbits[(0 * 512 + y0 + (t >> 3)) * 8 + (t & 7)] = 0ull;
        if (t == 0) gcnt[0 * 64 + bx] = 0;
    } else if (z == 5) {                  // border scale 12: zeros
        if (t < 64) rowbits[(12 * 512 + y0 + (t >> 3)) * 8 + (t & 7)] = 0ull;
        if (t == 0) gcnt[12 * 64 + bx] = 0;
    }

    const int p0 = sA - 1;
    float rm[4][8];                       // per-plane 3-row column max
    float vA[8], vB[8];                   // center values for scales sA, sA+1
#pragma unroll
    for (int pp = 0; pp < 4; ++pp) {
        if (pp == 3 && !hasB) {
#pragma unroll
            for (int k = 0; k < 8; ++k) rm[3][k] = -3.0e38f;
        } else {
            const float* dp = dog + (p0 + pp) * (512 * 512) + t;
            float val[10];
#pragma unroll
            for (int q = 0; q < 10; ++q) {
                int yy = y0 - 1 + q;
                val[q] = ((unsigned)yy < 512u) ? dp[yy * 512] : -3.0e38f;
            }
#pragma unroll
            for (int k = 0; k < 8; ++k)
                rm[pp][k] = fmaxf(val[k], fmaxf(val[k + 1], val[k + 2]));
            if (pp == 1) {
#pragma unroll
                for (int k = 0; k < 8; ++k) vA[k] = val[k + 1];
            }
            if (pp == 2) {
#pragma unroll
                for (int k = 0; k < 8; ++k) vB[k] = val[k + 1];
            }
        }
    }

    __shared__ float cml[2][8][512];      // 32 KB
    __shared__ int cnt[2][8][8];
#pragma unroll
    for (int k = 0; k < 8; ++k) {
        cml[0][k][t] = fmaxf(rm[0][k], fmaxf(rm[1][k], rm[2][k]));
        cml[1][k][t] = fmaxf(rm[1][k], fmaxf(rm[2][k], rm[3][k]));  // rm[3]=-3e38 when !hasB
    }
    __syncthreads();

#pragma unroll
    for (int k = 0; k < 8; ++k) {         // scale sA
        int y = y0 + k;
        bool peak = false;
        if (t >= 1 && t <= 510 && y >= 1 && y <= 510) {
            float v = vA[k];
            if (v > 0.001f) {
                float mx = fmaxf(cml[0][k][t - 1], fmaxf(cml[0][k][t], cml[0][k][t + 1]));
                peak = (v >= mx);         // mx includes v
            }
        }
        unsigned long long m = __ballot(peak);
        if (lane == 0) {
            rowbits[(sA * 512 + y) * 8 + w] = m;
            cnt[0][k][w] = __popcll(m);
        }
    }
    if (hasB) {
        const int sB = sA + 1;
#pragma unroll
        for (int k = 0; k < 8; ++k) {     // scale sA+1
            int y = y0 + k;
            bool peak = false;
            if (t >= 1 && t <= 510 && y >= 1 && y <= 510) {
                float v = vB[k];
                if (v > 0.001f) {
                    float mx = fmaxf(cml[1][k][t - 1], fmaxf(cml[1][k][t], cml[1][k][t + 1]));
                    peak = (v >= mx);
                }
            }
            unsigned long long m = __ballot(peak);
            if (lane == 0) {
                rowbits[(sB * 512 + y) * 8 + w] = m;
                cnt[1][k][w] = __popcll(m);
            }
        }
    }
    __syncthreads();
    if (t == 0) {
        int c = 0;
#pragma unroll
        for (int k = 0; k < 8; ++k)
#pragma unroll
            for (int q = 0; q < 8; ++q) c += cnt[0][k][q];
        gcnt[sA * 64 + bx] = c;
        if (hasB) {
            c = 0;
#pragma unroll
            for (int k = 0; k < 8; ++k)
#pragma unroll
                for (int q = 0; q < 8; ++q) c += cnt[1][k][q];
            gcnt[(sA + 1) * 64 + bx] = c;
        }
    }
}

// ---- 4: ordered emit + padding fill; wave-shuffle group reduce ----
// grid 832 blocks x 512 (block b covers scale b/64, rows (b%64)*8 .. +7)
__global__ __launch_bounds__(512) void emit(const unsigned long long* __restrict__ rowbits,
                                            const int* __restrict__ gcnt,
                                            const float* __restrict__ sigma_list,
                                            float* __restrict__ out) {
    const int b = blockIdx.x;
    const int s = b >> 6;
    const int y0 = (b & 63) * 8;
    const int t = threadIdx.x;
    const int w = t >> 6, lane = t & 63;

    // zero-peak blocks outside the padding range have nothing to do
    if (b >= 64 && gcnt[b] == 0) return;

    __shared__ unsigned long long m[64];   // [row k][word q]
    __shared__ int pre[64];                // exclusive word prefix (row-major)
    __shared__ int wsumA[8], wsumB[8];

    if (t < 64) m[t] = rowbits[(s * 512 + y0 + (t >> 3)) * 8 + (t & 7)];

    int pa = 0, pb = 0;
    {
        int c0 = (t < 832) ? gcnt[t] : 0;
        int i1 = t + 512;
        int c1 = (i1 < 832) ? gcnt[i1] : 0;
        pb = c0 + c1;
        if (t < b) pa += c0;
        if (i1 < b) pa += c1;
    }
#pragma unroll
    for (int off = 32; off > 0; off >>= 1) {   // 64-lane wave reduce
        pa += __shfl_down(pa, off);
        pb += __shfl_down(pb, off);
    }
    if (lane == 0) { wsumA[w] = pa; wsumB[w] = pb; }

    if (t < 64) {                          // wave-0 exclusive scan of word counts
        int wc = (int)__popcll(m[t]);
        int inc = wc;
        for (int off = 1; off < 64; off <<= 1) {
            int v = __shfl_up(inc, off);
            if (lane >= off) inc += v;
        }
        pre[t] = inc - wc;
    }
    __syncthreads();

    int gbase = 0, tot = 0;
#pragma unroll
    for (int i = 0; i < 8; ++i) { gbase += wsumA[i]; tot += wsumB[i]; }
    tot = min(tot, MAXPEAKS);

#pragma unroll
    for (int k = 0; k < 8; ++k) {
        int widx = k * 8 + (t >> 6);
        unsigned long long mw = m[widx];
        if ((mw >> lane) & 1ull) {
            int pos = gbase + pre[widx] + (int)__popcll(mw & ((1ull << lane) - 1ull));
            if (pos < MAXPEAKS) {
                out[pos * 3 + 0] = sigma_list[s];
                out[pos * 3 + 1] = (float)(y0 + k);
                out[pos * 3 + 2] = (float)t;
            }
        }
    }

    int idx = b * 512 + t;                 // blocks 0..63 cover all 32768 rows
    if (idx < MAXPEAKS && idx >= tot) {
        out[idx * 3 + 0] = sigma_list[0];
        out[idx * 3 + 1] = 0.0f;
        out[idx * 3 + 2] = 0.0f;
    }
}

extern "C" void kernel_launch(void* const* d_in, const int* in_sizes, int n_in,
                              void* d_out, int out_size, void* d_ws, size_t ws_size,
                              hipStream_t stream) {
    const float* x     = (const float*)d_in[0];   // [1,1,512,512]
    const float* sigma = (const float*)d_in[2];   // [14]
    float* out = (float*)d_out;                   // [32768,3]

    char* ws = (char*)d_ws;
    float* h                     = (float*)(ws + OFF_H);
    float* dog                   = (float*)(ws + OFF_DOG);
    unsigned long long* rowbits  = (unsigned long long*)(ws + OFF_BITS);
    int* gcnt                    = (int*)(ws + OFF_GCNT);

    hpass<<<dim3(64, 14), 256, 0, stream>>>(x, sigma, h);
    vdog<<<dim3(8, 32, 13), 64, 0, stream>>>(h, sigma, dog);
    detect<<<dim3(64, 6), 512, 0, stream>>>(dog, rowbits, gcnt);
    emit<<<832, 512, 0, stream>>>(rowbits, gcnt, sigma, out);
}